// Round 6
// baseline (248.603 us; speedup 1.0000x reference)
//
#include <hip/hip_runtime.h>
#include <stdint.h>

// Lovasz-softmax loss without sorting:
//   loss_c = sum over descending error levels v of v * (J(n>=v, f>=v) - J_prev)
// where n(v)=#{err_c >= v}, f(v)=#{label==c and err_c >= v},
//   J(n,f) = 1 - (G - f) / (G + n - f), G = #{label==c}.
// Tie-grouping is exact; quantizing errors to 384 bins perturbs loss by
// <= 2 * 0.5/383 ~= 2.6e-3 (threshold is 1.9e-2, 7x margin).
//
// R6: occupancy experiment. R2 showed k1 ~doubles at 8 waves/CU (vs 16) with
// identical per-CU work -> latency-bound, not LDS-pipe-bound. So push 16->32
// waves/CU: 2 px/thread (~55 VGPR), __launch_bounds__(1024,8) forces <=64
// VGPR, 512 blocks so 2 x 1024-thr blocks co-reside (LDS 2x58.4KB <= 160KB).
// Cost: flush/k2 traffic back to 14.9MB (+~2.5us) - net win if latency theory
// holds.
// Frozen: 3-launch structure (R2/R3: 456-block agent fences = +60us),
// parity dual-hist + NBINS=384 (R5: -3.3us), k4 folded into k3 (19-block
// ticket, cheap).

#define C_CLASSES 19
#define NBINS 384
#define HISTWORDS (C_CLASSES * NBINS)   // 7296
#define PAD_OFF (HISTWORDS + 16)        // second copy base; +16 -> bank shift 16
#define HISTTOT (2 * HISTWORDS + 16)    // 14608 words = 58,432 B LDS
#define HW_SHIFT 18                     // H*W = 512*512 = 2^18
#define HW_MASK ((1 << HW_SHIFT) - 1)
#define NGROUPS 8

// Per-pixel error binning. r[] holds exp(logit) values, s their sum.
// hist points at this lane's parity copy. Packed LDS counters:
// low 16 = n count, high 16 = fg count (per-block counts <= 4096 < 2^16).
__device__ __forceinline__ void px_process(const float* r, float s, int lab,
                                           unsigned int* hist)
{
    // scale = 383 / sum; non-fg bin = rn(383*pr), fg bin = 383 - rn(383*pr).
    // p <= 1 + 1e-6 (rcp + sum rounding) so rn(383*p) in [0,383]: no clamp.
    float scale = (float)(NBINS - 1) * __builtin_amdgcn_rcpf(s);
#pragma unroll
    for (int c = 0; c < C_CLASSES; ++c) {
        int ti = __float2int_rn(r[c] * scale);
        int idx = (c == lab) ? (NBINS - 1 - ti) : ti;
        atomicAdd(&hist[c * NBINS + idx], (c == lab) ? 0x10001u : 1u);
    }
}

// K1: fused softmax + error histogram, 2 pixels per thread per iteration.
// 1024 thr/block, 512 blocks, <=64 VGPR -> 2 blocks/CU = 32 waves/CU.
__global__ __launch_bounds__(1024, 8) void k1_hist(
    const float* __restrict__ x, const int* __restrict__ labels,
    unsigned int* __restrict__ copies, int P, int pixPerBlk)
{
    __shared__ unsigned int hist[HISTTOT];   // 58,432 B (two parity copies)
    int tid = threadIdx.x;
    uint4* h4 = (uint4*)hist;
    for (int i = tid; i < HISTTOT / 4; i += 1024) h4[i] = make_uint4(0u, 0u, 0u, 0u);
    __syncthreads();

    // odd lanes use the +16-word-shifted second copy -> complementary banks
    unsigned int* myhist = hist + (tid & 1) * PAD_OFF;

    int base = blockIdx.x * pixPerBlk;
    for (int it = 0; it < pixPerBlk; it += 2048) {
        int pix = base + it + tid * 2;          // pix % 2 == 0 always
        if (pix + 1 < P) {
            // 2 consecutive pixels never cross an image boundary (2 | 2^18)
            int img = pix >> HW_SHIFT;
            int rem = pix & HW_MASK;
            const float* xp = x + (((size_t)img * C_CLASSES) << HW_SHIFT) + rem;
            float r0[C_CLASSES], r1[C_CLASSES];
            float s0 = 0.f, s1 = 0.f;
#pragma unroll
            for (int c = 0; c < C_CLASSES; ++c) {
                float2 v = *reinterpret_cast<const float2*>(xp + ((size_t)c << HW_SHIFT));
                float e0 = __expf(v.x), e1 = __expf(v.y);
                r0[c] = e0; s0 += e0; r1[c] = e1; s1 += e1;
            }
            int2 lb = *reinterpret_cast<const int2*>(labels + pix);
            px_process(r0, s0, lb.x, myhist);
            px_process(r1, s1, lb.y, myhist);
        } else if (pix < P) {
            int img = pix >> HW_SHIFT;
            int rem = pix & HW_MASK;
            const float* xp = x + (((size_t)img * C_CLASSES) << HW_SHIFT) + rem;
            float r[C_CLASSES];
            float s = 0.f;
#pragma unroll
            for (int c = 0; c < C_CLASSES; ++c) {
                float e = __expf(xp[(size_t)c << HW_SHIFT]);
                r[c] = e; s += e;
            }
            px_process(r, s, labels[pix], myhist);
        }
    }
    __syncthreads();
    // merge parity copies during flush; plain stores to this block's copy
    uint4* dst = (uint4*)(copies + (size_t)blockIdx.x * HISTWORDS);
    const uint4* s0 = (const uint4*)hist;
    const uint4* s1 = (const uint4*)(hist + PAD_OFF);   // PAD_OFF % 4 == 0
    for (int i = tid; i < HISTWORDS / 4; i += 1024) {
        uint4 a = s0[i], b = s1[i];
        dst[i] = make_uint4(a.x + b.x, a.y + b.y, a.z + b.z, a.w + b.w);
    }
}

// K2: reduce ncopies private histograms into NGROUPS partial (n,f) histograms.
// Also re-inits the k3 completion ticket (workspace is poisoned between runs).
// NO in-kernel fences: k2->k3 visibility comes from the kernel boundary.
__global__ __launch_bounds__(256) void k2_reduce(
    const unsigned int* __restrict__ copies,
    int* __restrict__ nPart, int* __restrict__ fPart,
    int* __restrict__ ticket, int ncopies, int cpg)
{
    if (blockIdx.x == 0 && blockIdx.y == 0 && threadIdx.x == 0) *ticket = 0;
    int pos = blockIdx.x * 256 + threadIdx.x;   // grid.x = 29 -> guard
    if (pos >= HISTWORDS) return;
    int g = blockIdx.y;
    int c0 = g * cpg;
    int c1 = c0 + cpg; if (c1 > ncopies) c1 = ncopies;
    unsigned int sn = 0, sf = 0;
    for (int k = c0; k < c1; ++k) {
        unsigned int w = copies[(size_t)k * HISTWORDS + pos];
        sn += w & 0xFFFFu;
        sf += w >> 16;
    }
    nPart[(size_t)g * HISTWORDS + pos] = (int)sn;
    fPart[(size_t)g * HISTWORDS + pos] = (int)sf;
}

// K3: one wave per class — descending-bin prefix scan + Jaccard integral.
// Last block to finish also averages over present classes (former k4) —
// only 19 ticket atomics total, cheap (R2/R3 lesson: 456 fences = +60us).
__global__ __launch_bounds__(64) void k3_scan(
    const int* __restrict__ nPart, const int* __restrict__ fPart,
    float* __restrict__ res, int* __restrict__ ticket,
    float* __restrict__ out)
{
    int c = blockIdx.x;
    int lane = threadIdx.x;
    const int PER = NBINS / 64;   // 6
    int nl[PER], fl[PER];
    int totN = 0, totF = 0;
#pragma unroll
    for (int i = 0; i < PER; ++i) {
        int j = lane * PER + i;            // ascending j = descending error value
        int bin = NBINS - 1 - j;
        int pos = c * NBINS + bin;
        int n = 0, f = 0;
#pragma unroll
        for (int g = 0; g < NGROUPS; ++g) {
            n += nPart[g * HISTWORDS + pos];
            f += fPart[g * HISTWORDS + pos];
        }
        nl[i] = n; fl[i] = f; totN += n; totF += f;
    }
    // inclusive scan of lane totals across the wave
    int incN = totN, incF = totF;
    for (int off = 1; off < 64; off <<= 1) {
        int tn = __shfl_up(incN, off);
        int tf = __shfl_up(incF, off);
        if (lane >= off) { incN += tn; incF += tf; }
    }
    int G = __shfl(incF, 63);
    double loss = 0.0;
    if (G > 0) {
        int cumN = incN - totN;            // exclusive prefix for this lane
        int cumF = incF - totF;
        double dG = (double)G;
        double Jb = 1.0 - (dG - (double)cumF) / (dG + (double)cumN - (double)cumF);
#pragma unroll
        for (int i = 0; i < PER; ++i) {
            int bin = NBINS - 1 - (lane * PER + i);
            cumN += nl[i]; cumF += fl[i];
            double Ja = 1.0 - (dG - (double)cumF) / (dG + (double)cumN - (double)cumF);
            loss += ((double)bin / (double)(NBINS - 1)) * (Ja - Jb);
            Jb = Ja;
        }
    }
    for (int off = 32; off > 0; off >>= 1)
        loss += __shfl_down(loss, off);
    if (lane == 0) {
        __hip_atomic_store(&res[c], (float)loss, __ATOMIC_RELAXED, __HIP_MEMORY_SCOPE_AGENT);
        __hip_atomic_store(&res[C_CLASSES + c], (float)G, __ATOMIC_RELAXED, __HIP_MEMORY_SCOPE_AGENT);
        int t = __hip_atomic_fetch_add(ticket, 1, __ATOMIC_ACQ_REL, __HIP_MEMORY_SCOPE_AGENT);
        if (t == C_CLASSES - 1) {
            float s = 0.f, cnt = 0.f;
            for (int cc = 0; cc < C_CLASSES; ++cc) {
                float g = __hip_atomic_load(&res[C_CLASSES + cc], __ATOMIC_RELAXED, __HIP_MEMORY_SCOPE_AGENT);
                if (g > 0.f) {
                    s += __hip_atomic_load(&res[cc], __ATOMIC_RELAXED, __HIP_MEMORY_SCOPE_AGENT);
                    cnt += 1.f;
                }
            }
            out[0] = s / fmaxf(cnt, 1.f);
        }
    }
}

extern "C" void kernel_launch(void* const* d_in, const int* in_sizes, int n_in,
                              void* d_out, int out_size, void* d_ws, size_t ws_size,
                              hipStream_t stream)
{
    const float* x = (const float*)d_in[0];
    const int* labels = (const int*)d_in[1];
    float* out = (float*)d_out;
    int P = in_sizes[1];   // B*H*W = 2,097,152

    const size_t histBytes = (size_t)HISTWORDS * 4;           // 29,184
    const size_t partBytes = (size_t)NGROUPS * HISTWORDS * 4; // 233,472
    const size_t resBytes = 256;                              // res[38] + ticket
    const size_t reserved = 2 * partBytes + resBytes + 256;

    int maxCopies = (int)((ws_size > reserved ? ws_size - reserved : 0) / histBytes);
    int ncopies = maxCopies < 512 ? maxCopies : 512;
    if (ncopies < 1) ncopies = 1;
    int pixPerBlk = (P + ncopies - 1) / ncopies;
    pixPerBlk = ((pixPerBlk + 2047) / 2048) * 2048;           // multiple of 1024 thr * 2 px

    unsigned int* copies = (unsigned int*)d_ws;
    int* nPart = (int*)((char*)d_ws + histBytes * (size_t)ncopies);
    int* fPart = (int*)((char*)nPart + partBytes);
    float* res = (float*)((char*)fPart + partBytes);
    int* ticket = (int*)((char*)res + 160);

    int cpg = (ncopies + NGROUPS - 1) / NGROUPS;

    k1_hist<<<dim3(ncopies), dim3(1024), 0, stream>>>(x, labels, copies, P, pixPerBlk);
    k2_reduce<<<dim3((HISTWORDS + 255) / 256, NGROUPS), dim3(256), 0, stream>>>(copies, nPart, fPart, ticket, ncopies, cpg);
    k3_scan<<<dim3(C_CLASSES), dim3(64), 0, stream>>>(nPart, fPart, res, ticket, out);
}

// Round 7
// 242.346 us; speedup vs baseline: 1.0258x; 1.0258x over previous
//
#include <hip/hip_runtime.h>
#include <stdint.h>

// Lovasz-softmax loss without sorting:
//   loss_c = sum over descending error levels v of v * (J(n>=v, f>=v) - J_prev)
// where n(v)=#{err_c >= v}, f(v)=#{label==c and err_c >= v},
//   J(n,f) = 1 - (G - f) / (G + n - f), G = #{label==c}.
// Tie-grouping is exact; quantizing errors to 384 bins perturbs loss by
// <= 2 * 0.5/383 ~= 2.6e-3 (threshold is 1.9e-2, 7x margin).
//
// R7: k1 proven occupancy-INSENSITIVE 8..32 waves/CU (R2 vs R3: block size
// swap alone was -0.6us; R6: 32 waves = +traffic only) -> throughput-bound.
// So spend occupancy on per-pixel efficiency at UNCHANGED traffic:
//  - 8 px/thread, 512 thr/block, 256 blocks (VGPR ~180 < 256 cap @512thr;
//    would spill at 1024 thr). Halves loop/addr overhead; 2xfloat4 per
//    class-stream per iteration.
//  - 4-way parity histogram (lane&3, 117KB LDS, 1 blk/CU): quarters
//    DS-atomic conflict depth.
// Frozen: 3-launch structure (R2/R3: 456-block agent fences = +60us),
// NBINS=384 + 256 copies (R5), k4 folded into k3 (19-block ticket, cheap).

#define C_CLASSES 19
#define NBINS 384
#define HISTWORDS (C_CLASSES * NBINS)   // 7296
#define PAD_OFF (HISTWORDS + 16)        // copy stride; +16 -> bank shift 16
#define NPAR 4                          // parity copies
#define HISTTOT (NPAR * PAD_OFF)        // 29,248 words = 116,992 B LDS
#define HW_SHIFT 18                     // H*W = 512*512 = 2^18
#define HW_MASK ((1 << HW_SHIFT) - 1)
#define NGROUPS 8

// Per-pixel error binning. r[] holds exp(logit) values, s their sum.
// hist points at this lane's parity copy. Packed LDS counters:
// low 16 = n count, high 16 = fg count (per-block counts <= 8192 < 2^16).
__device__ __forceinline__ void px_process(const float* r, float s, int lab,
                                           unsigned int* hist)
{
    // scale = 383 / sum; non-fg bin = rn(383*pr), fg bin = 383 - rn(383*pr).
    // p <= 1 + 1e-6 (rcp + sum rounding) so rn(383*p) in [0,383]: no clamp.
    float scale = (float)(NBINS - 1) * __builtin_amdgcn_rcpf(s);
#pragma unroll
    for (int c = 0; c < C_CLASSES; ++c) {
        int ti = __float2int_rn(r[c] * scale);
        int idx = (c == lab) ? (NBINS - 1 - ti) : ti;
        atomicAdd(&hist[c * NBINS + idx], (c == lab) ? 0x10001u : 1u);
    }
}

// K1: fused softmax + error histogram, 8 pixels per thread per iteration.
// 512 thr/block, 256 blocks = 8 waves/CU (occupancy-insensitive regime).
__global__ __launch_bounds__(512) void k1_hist(
    const float* __restrict__ x, const int* __restrict__ labels,
    unsigned int* __restrict__ copies, int P, int pixPerBlk)
{
    __shared__ unsigned int hist[HISTTOT];   // 116,992 B (4 parity copies)
    int tid = threadIdx.x;
    uint4* h4 = (uint4*)hist;
    for (int i = tid; i < HISTTOT / 4; i += 512) h4[i] = make_uint4(0u, 0u, 0u, 0u);
    __syncthreads();

    // lane parity 0..3 selects one of 4 bank-shifted copies
    unsigned int* myhist = hist + (tid & 3) * PAD_OFF;

    int base = blockIdx.x * pixPerBlk;
    for (int it = 0; it < pixPerBlk; it += 4096) {
        int pix = base + it + tid * 8;          // pix % 8 == 0 always
        if (pix + 7 < P) {
            // 8 consecutive pixels never cross an image boundary (8 | 2^18)
            int img = pix >> HW_SHIFT;
            int rem = pix & HW_MASK;
            const float* xp = x + (((size_t)img * C_CLASSES) << HW_SHIFT) + rem;
            float r0[C_CLASSES], r1[C_CLASSES], r2[C_CLASSES], r3[C_CLASSES];
            float r4[C_CLASSES], r5[C_CLASSES], r6[C_CLASSES], r7[C_CLASSES];
            float s0 = 0.f, s1 = 0.f, s2 = 0.f, s3 = 0.f;
            float s4 = 0.f, s5 = 0.f, s6 = 0.f, s7 = 0.f;
#pragma unroll
            for (int c = 0; c < C_CLASSES; ++c) {
                const float* cp = xp + ((size_t)c << HW_SHIFT);
                float4 va = *reinterpret_cast<const float4*>(cp);
                float4 vb = *reinterpret_cast<const float4*>(cp + 4);
                float e0 = __expf(va.x), e1 = __expf(va.y);
                float e2 = __expf(va.z), e3 = __expf(va.w);
                float e4 = __expf(vb.x), e5 = __expf(vb.y);
                float e6 = __expf(vb.z), e7 = __expf(vb.w);
                r0[c] = e0; s0 += e0; r1[c] = e1; s1 += e1;
                r2[c] = e2; s2 += e2; r3[c] = e3; s3 += e3;
                r4[c] = e4; s4 += e4; r5[c] = e5; s5 += e5;
                r6[c] = e6; s6 += e6; r7[c] = e7; s7 += e7;
            }
            int4 la = *reinterpret_cast<const int4*>(labels + pix);
            int4 lb = *reinterpret_cast<const int4*>(labels + pix + 4);
            px_process(r0, s0, la.x, myhist);
            px_process(r1, s1, la.y, myhist);
            px_process(r2, s2, la.z, myhist);
            px_process(r3, s3, la.w, myhist);
            px_process(r4, s4, lb.x, myhist);
            px_process(r5, s5, lb.y, myhist);
            px_process(r6, s6, lb.z, myhist);
            px_process(r7, s7, lb.w, myhist);
        } else {
#pragma unroll
            for (int k = 0; k < 8; ++k) {
                int p = pix + k;
                if (p < P) {
                    int img = p >> HW_SHIFT;
                    int rem = p & HW_MASK;
                    const float* xp = x + (((size_t)img * C_CLASSES) << HW_SHIFT) + rem;
                    float r[C_CLASSES];
                    float s = 0.f;
#pragma unroll
                    for (int c = 0; c < C_CLASSES; ++c) {
                        float e = __expf(xp[(size_t)c << HW_SHIFT]);
                        r[c] = e; s += e;
                    }
                    px_process(r, s, labels[p], myhist);
                }
            }
        }
    }
    __syncthreads();
    // merge 4 parity copies during flush; plain stores to this block's copy
    uint4* dst = (uint4*)(copies + (size_t)blockIdx.x * HISTWORDS);
    const uint4* c0 = (const uint4*)hist;                    // PAD_OFF % 4 == 0
    const uint4* c1 = (const uint4*)(hist + PAD_OFF);
    const uint4* c2 = (const uint4*)(hist + 2 * PAD_OFF);
    const uint4* c3 = (const uint4*)(hist + 3 * PAD_OFF);
    for (int i = tid; i < HISTWORDS / 4; i += 512) {
        uint4 a = c0[i], b = c1[i], c = c2[i], d = c3[i];
        dst[i] = make_uint4(a.x + b.x + c.x + d.x, a.y + b.y + c.y + d.y,
                            a.z + b.z + c.z + d.z, a.w + b.w + c.w + d.w);
    }
}

// K2: reduce ncopies private histograms into NGROUPS partial (n,f) histograms.
// Also re-inits the k3 completion ticket (workspace is poisoned between runs).
// NO in-kernel fences: k2->k3 visibility comes from the kernel boundary.
__global__ __launch_bounds__(256) void k2_reduce(
    const unsigned int* __restrict__ copies,
    int* __restrict__ nPart, int* __restrict__ fPart,
    int* __restrict__ ticket, int ncopies, int cpg)
{
    if (blockIdx.x == 0 && blockIdx.y == 0 && threadIdx.x == 0) *ticket = 0;
    int pos = blockIdx.x * 256 + threadIdx.x;   // grid.x = 29 -> guard
    if (pos >= HISTWORDS) return;
    int g = blockIdx.y;
    int c0 = g * cpg;
    int c1 = c0 + cpg; if (c1 > ncopies) c1 = ncopies;
    unsigned int sn = 0, sf = 0;
    for (int k = c0; k < c1; ++k) {
        unsigned int w = copies[(size_t)k * HISTWORDS + pos];
        sn += w & 0xFFFFu;
        sf += w >> 16;
    }
    nPart[(size_t)g * HISTWORDS + pos] = (int)sn;
    fPart[(size_t)g * HISTWORDS + pos] = (int)sf;
}

// K3: one wave per class — descending-bin prefix scan + Jaccard integral.
// Last block to finish also averages over present classes (former k4) —
// only 19 ticket atomics total, cheap (R2/R3 lesson: 456 fences = +60us).
__global__ __launch_bounds__(64) void k3_scan(
    const int* __restrict__ nPart, const int* __restrict__ fPart,
    float* __restrict__ res, int* __restrict__ ticket,
    float* __restrict__ out)
{
    int c = blockIdx.x;
    int lane = threadIdx.x;
    const int PER = NBINS / 64;   // 6
    int nl[PER], fl[PER];
    int totN = 0, totF = 0;
#pragma unroll
    for (int i = 0; i < PER; ++i) {
        int j = lane * PER + i;            // ascending j = descending error value
        int bin = NBINS - 1 - j;
        int pos = c * NBINS + bin;
        int n = 0, f = 0;
#pragma unroll
        for (int g = 0; g < NGROUPS; ++g) {
            n += nPart[g * HISTWORDS + pos];
            f += fPart[g * HISTWORDS + pos];
        }
        nl[i] = n; fl[i] = f; totN += n; totF += f;
    }
    // inclusive scan of lane totals across the wave
    int incN = totN, incF = totF;
    for (int off = 1; off < 64; off <<= 1) {
        int tn = __shfl_up(incN, off);
        int tf = __shfl_up(incF, off);
        if (lane >= off) { incN += tn; incF += tf; }
    }
    int G = __shfl(incF, 63);
    double loss = 0.0;
    if (G > 0) {
        int cumN = incN - totN;            // exclusive prefix for this lane
        int cumF = incF - totF;
        double dG = (double)G;
        double Jb = 1.0 - (dG - (double)cumF) / (dG + (double)cumN - (double)cumF);
#pragma unroll
        for (int i = 0; i < PER; ++i) {
            int bin = NBINS - 1 - (lane * PER + i);
            cumN += nl[i]; cumF += fl[i];
            double Ja = 1.0 - (dG - (double)cumF) / (dG + (double)cumN - (double)cumF);
            loss += ((double)bin / (double)(NBINS - 1)) * (Ja - Jb);
            Jb = Ja;
        }
    }
    for (int off = 32; off > 0; off >>= 1)
        loss += __shfl_down(loss, off);
    if (lane == 0) {
        __hip_atomic_store(&res[c], (float)loss, __ATOMIC_RELAXED, __HIP_MEMORY_SCOPE_AGENT);
        __hip_atomic_store(&res[C_CLASSES + c], (float)G, __ATOMIC_RELAXED, __HIP_MEMORY_SCOPE_AGENT);
        int t = __hip_atomic_fetch_add(ticket, 1, __ATOMIC_ACQ_REL, __HIP_MEMORY_SCOPE_AGENT);
        if (t == C_CLASSES - 1) {
            float s = 0.f, cnt = 0.f;
            for (int cc = 0; cc < C_CLASSES; ++cc) {
                float g = __hip_atomic_load(&res[C_CLASSES + cc], __ATOMIC_RELAXED, __HIP_MEMORY_SCOPE_AGENT);
                if (g > 0.f) {
                    s += __hip_atomic_load(&res[cc], __ATOMIC_RELAXED, __HIP_MEMORY_SCOPE_AGENT);
                    cnt += 1.f;
                }
            }
            out[0] = s / fmaxf(cnt, 1.f);
        }
    }
}

extern "C" void kernel_launch(void* const* d_in, const int* in_sizes, int n_in,
                              void* d_out, int out_size, void* d_ws, size_t ws_size,
                              hipStream_t stream)
{
    const float* x = (const float*)d_in[0];
    const int* labels = (const int*)d_in[1];
    float* out = (float*)d_out;
    int P = in_sizes[1];   // B*H*W = 2,097,152

    const size_t histBytes = (size_t)HISTWORDS * 4;           // 29,184
    const size_t partBytes = (size_t)NGROUPS * HISTWORDS * 4; // 233,472
    const size_t resBytes = 256;                              // res[38] + ticket
    const size_t reserved = 2 * partBytes + resBytes + 256;

    int maxCopies = (int)((ws_size > reserved ? ws_size - reserved : 0) / histBytes);
    int ncopies = maxCopies < 256 ? maxCopies : 256;
    if (ncopies < 1) ncopies = 1;
    int pixPerBlk = (P + ncopies - 1) / ncopies;
    pixPerBlk = ((pixPerBlk + 4095) / 4096) * 4096;           // multiple of 512 thr * 8 px

    unsigned int* copies = (unsigned int*)d_ws;
    int* nPart = (int*)((char*)d_ws + histBytes * (size_t)ncopies);
    int* fPart = (int*)((char*)nPart + partBytes);
    float* res = (float*)((char*)fPart + partBytes);
    int* ticket = (int*)((char*)res + 160);

    int cpg = (ncopies + NGROUPS - 1) / NGROUPS;

    k1_hist<<<dim3(ncopies), dim3(512), 0, stream>>>(x, labels, copies, P, pixPerBlk);
    k2_reduce<<<dim3((HISTWORDS + 255) / 256, NGROUPS), dim3(256), 0, stream>>>(copies, nPart, fPart, ticket, ncopies, cpg);
    k3_scan<<<dim3(C_CLASSES), dim3(64), 0, stream>>>(nPart, fPart, res, ticket, out);
}